// Round 1
// baseline (1058.142 us; speedup 1.0000x reference)
//
#include <hip/hip_runtime.h>

#define T 32
#define C 2048
#define NTOT 600
#define NCLASS 20
#define NSUP 5
#define PER 30
#define NQPC 25
#define NQ 500
#define NQROWS (NQ * T)      // 16000
#define NPROWS (NCLASS * T)  // 640
#define GAMMA 0.1f
#define INVG 10.0f
#define BIG 1e10f

// ---------------- stable counting sort + query source indices ----------------
__global__ void sort_kernel(const int* __restrict__ target, int* __restrict__ order,
                            int* __restrict__ qsrc) {
    if (blockIdx.x != 0 || threadIdx.x != 0) return;
    int cnt[NCLASS];
    for (int c = 0; c < NCLASS; c++) cnt[c] = 0;
    for (int i = 0; i < NTOT; i++) cnt[target[i]]++;
    int off[NCLASS];
    int run = 0;
    for (int c = 0; c < NCLASS; c++) { off[c] = run; run += cnt[c]; }
    for (int i = 0; i < NTOT; i++) { int c = target[i]; order[off[c]++] = i; }
    for (int q = 0; q < NQ; q++) {
        int cls = q / NQPC, w = q % NQPC;
        qsrc[q] = order[cls * PER + NSUP + w];
    }
}

// ---------------- prototypes: mean over support ----------------
__global__ void proto_kernel(const float* __restrict__ inp, const int* __restrict__ order,
                             float* __restrict__ proto) {
    int idx = blockIdx.x * 256 + threadIdx.x;  // exactly NCLASS*T*C threads
    int cls = idx / (T * C);
    int rem = idx % (T * C);
    float s = 0.f;
#pragma unroll
    for (int sup = 0; sup < NSUP; sup++) {
        int src = order[cls * PER + sup];
        s += inp[(size_t)src * (T * C) + rem];
    }
    proto[idx] = s / 5.0f;
}

// ---------------- squared row norms (wave per row) ----------------
__global__ void rownorm_q_kernel(const float* __restrict__ inp, const int* __restrict__ qsrc,
                                 float* __restrict__ x2) {
    int w = (int)((blockIdx.x * (size_t)blockDim.x + threadIdx.x) >> 6);
    int lane = threadIdx.x & 63;
    if (w >= NQROWS) return;
    int q = w >> 5, i = w & 31;
    const float* p = inp + (size_t)qsrc[q] * (T * C) + (size_t)i * C;
    float s = 0.f;
#pragma unroll
    for (int k0 = 0; k0 < C; k0 += 256) {
        float4 v = *(const float4*)(p + k0 + lane * 4);
        s += v.x * v.x + v.y * v.y + v.z * v.z + v.w * v.w;
    }
#pragma unroll
    for (int off = 32; off; off >>= 1) s += __shfl_xor(s, off);
    if (lane == 0) x2[w] = s;
}

__global__ void rownorm_p_kernel(const float* __restrict__ proto, float* __restrict__ y2) {
    int w = (int)((blockIdx.x * (size_t)blockDim.x + threadIdx.x) >> 6);
    int lane = threadIdx.x & 63;
    if (w >= NPROWS) return;
    const float* p = proto + (size_t)w * C;
    float s = 0.f;
#pragma unroll
    for (int k0 = 0; k0 < C; k0 += 256) {
        float4 v = *(const float4*)(p + k0 + lane * 4);
        s += v.x * v.x + v.y * v.y + v.z * v.z + v.w * v.w;
    }
#pragma unroll
    for (int off = 32; off; off >>= 1) s += __shfl_xor(s, off);
    if (lane == 0) y2[w] = s;
}

// ---------------- big GEMM: xy[16000][640] = ZQ(gathered) x Proto^T ----------------
__global__ __launch_bounds__(256) void gemm_xy_kernel(const float* __restrict__ inp,
                                                      const float* __restrict__ proto,
                                                      const int* __restrict__ qsrc,
                                                      float* __restrict__ xy) {
    __shared__ float As[16][64];
    __shared__ float Bs[16][64];
    __shared__ int arow[64];
    int tid = threadIdx.x;
    int bm = blockIdx.x, bn = blockIdx.y;
    if (tid < 64) {
        int r = bm * 64 + tid;
        arow[tid] = qsrc[r >> 5] * (T * C) + (r & 31) * C;
    }
    __syncthreads();
    int lr = tid >> 2;          // 0..63: tile row to load
    int lk = (tid & 3) << 2;    // k offset within 16
    int tm = (tid >> 4) << 2;   // 0..60: output row micro-tile
    int tn = (tid & 15) << 2;   // 0..60: output col micro-tile
    int aoff = arow[lr];
    const float* brow = proto + (size_t)(bn * 64 + lr) * C;
    float acc[4][4] = {};
    for (int k0 = 0; k0 < C; k0 += 16) {
        float4 av = *(const float4*)(inp + (size_t)aoff + k0 + lk);
        float4 bv = *(const float4*)(brow + k0 + lk);
        __syncthreads();
        As[lk + 0][lr] = av.x; As[lk + 1][lr] = av.y; As[lk + 2][lr] = av.z; As[lk + 3][lr] = av.w;
        Bs[lk + 0][lr] = bv.x; Bs[lk + 1][lr] = bv.y; Bs[lk + 2][lr] = bv.z; Bs[lk + 3][lr] = bv.w;
        __syncthreads();
#pragma unroll
        for (int k = 0; k < 16; k++) {
            float4 a = *(const float4*)&As[k][tm];
            float4 b = *(const float4*)&Bs[k][tn];
            acc[0][0] += a.x * b.x; acc[0][1] += a.x * b.y; acc[0][2] += a.x * b.z; acc[0][3] += a.x * b.w;
            acc[1][0] += a.y * b.x; acc[1][1] += a.y * b.y; acc[1][2] += a.y * b.z; acc[1][3] += a.y * b.w;
            acc[2][0] += a.z * b.x; acc[2][1] += a.z * b.y; acc[2][2] += a.z * b.z; acc[2][3] += a.z * b.w;
            acc[3][0] += a.w * b.x; acc[3][1] += a.w * b.y; acc[3][2] += a.w * b.z; acc[3][3] += a.w * b.w;
        }
    }
#pragma unroll
    for (int ii = 0; ii < 4; ii++) {
        int r = bm * 64 + tm + ii;
        float4 o = make_float4(acc[ii][0], acc[ii][1], acc[ii][2], acc[ii][3]);
        *(float4*)&xy[(size_t)r * NPROWS + bn * 64 + tn] = o;
    }
}

// ---------------- batched SYRK: G[mat] = A A^T for 32x2048 A ----------------
__global__ __launch_bounds__(256) void syrk_kernel(const float* __restrict__ srcbase,
                                                   const int* __restrict__ qsrc,
                                                   float* __restrict__ gout, int mode) {
    int mat = blockIdx.x;
    const float* src = (mode == 0) ? srcbase + (size_t)qsrc[mat] * (T * C)
                                   : srcbase + (size_t)mat * (T * C);
    __shared__ float As[64][32];  // k-major
    int tid = threadIdx.x;
    int row = tid >> 3;           // 0..31 (load + compute i)
    int kof = (tid & 7) * 8;      // 0..56
    int j4 = (tid & 7) * 4;       // 0..28
    float acc[4] = {};
    for (int k0 = 0; k0 < C; k0 += 64) {
        float4 v0 = *(const float4*)(src + (size_t)row * C + k0 + kof);
        float4 v1 = *(const float4*)(src + (size_t)row * C + k0 + kof + 4);
        __syncthreads();
        As[kof + 0][row] = v0.x; As[kof + 1][row] = v0.y; As[kof + 2][row] = v0.z; As[kof + 3][row] = v0.w;
        As[kof + 4][row] = v1.x; As[kof + 5][row] = v1.y; As[kof + 6][row] = v1.z; As[kof + 7][row] = v1.w;
        __syncthreads();
#pragma unroll
        for (int k = 0; k < 64; k++) {
            float a = As[k][row];
            float4 b = *(const float4*)&As[k][j4];
            acc[0] += a * b.x; acc[1] += a * b.y; acc[2] += a * b.z; acc[3] += a * b.w;
        }
    }
    float* o = gout + (size_t)mat * (T * T) + row * T + j4;
    o[0] = acc[0]; o[1] = acc[1]; o[2] = acc[2]; o[3] = acc[3];
}

// ---------------- soft-DTW DP: one thread per 32x32 cost matrix ----------------
__global__ void softdtw_kernel(const float* __restrict__ cmat, const float* __restrict__ rterm_all,
                               const float* __restrict__ cterm_all, float* __restrict__ out,
                               int mode, int count) {
    int mm = blockIdx.x * 64 + threadIdx.x;
    if (mm >= count) return;
    const float* rterm;
    const float* cterm;
    const float* cptr;
    int cstride;
    if (mode == 0) {  // cross: cmat = xy[16000][640]
        int q = mm / NCLASS, m = mm % NCLASS;
        rterm = rterm_all + q * T;
        cterm = cterm_all + m * T;
        cptr = cmat + (size_t)(q * T) * NPROWS + m * T;
        cstride = NPROWS;
    } else {  // self: cmat = G[mm][32][32]
        rterm = rterm_all + mm * T;
        cterm = cterm_all + mm * T;
        cptr = cmat + (size_t)mm * (T * T);
        cstride = T;
    }
    float cj[T];
#pragma unroll
    for (int j = 0; j < T; j++) cj[j] = cterm[j];
    float Rp[T + 1];
    Rp[0] = 0.f;
#pragma unroll
    for (int j = 1; j <= T; j++) Rp[j] = BIG;
    for (int i = 0; i < T; i++) {
        float diag = Rp[0];
        Rp[0] = BIG;
        float left = BIG;
        float ai = rterm[i];
        const float* crow = cptr + (size_t)i * cstride;
#pragma unroll
        for (int j = 0; j < T; j++) {
            float up = Rp[j + 1];
            float d = ai + cj[j] - 2.0f * crow[j];
            float mn = fminf(diag, fminf(up, left));
            float ssum = __expf((mn - diag) * INVG) + __expf((mn - up) * INVG) +
                         __expf((mn - left) * INVG);
            float r = d + mn - GAMMA * __logf(ssum);
            diag = up;
            Rp[j + 1] = r;
            left = r;
        }
    }
    out[mm] = Rp[T];
}

// ---------------- finalize: dist, log-softmax, loss, acc ----------------
__global__ __launch_bounds__(512) void finalize_kernel(const float* __restrict__ dxy,
                                                       const float* __restrict__ dxx,
                                                       const float* __restrict__ dyy,
                                                       float* __restrict__ out) {
    __shared__ float sl[512];
    __shared__ float sa[512];
    int q = threadIdx.x;
    float bl = 0.f, fl = 0.f;
    if (q < NQ) {
        float dxxq = dxx[q];
        int cq = q / NQPC;
        float dd[NCLASS];
#pragma unroll
        for (int m = 0; m < NCLASS; m++)
            dd[m] = dxy[q * NCLASS + m] - 0.5f * (dxxq + dyy[m]);
        float best = dd[0];
        int bi = 0;
#pragma unroll
        for (int m = 1; m < NCLASS; m++) {
            if (dd[m] < best) { best = dd[m]; bi = m; }
        }
        float s = 0.f;
        float dcq = dd[0];
#pragma unroll
        for (int m = 0; m < NCLASS; m++) {
            s += __expf(best - dd[m]);
            if (m == cq) dcq = dd[m];  // static-index extraction (no scratch)
        }
        float lse = __logf(s) - best;
        bl = dcq + lse;
        out[2 + q] = bl;
        fl = (bi == cq) ? 1.f : 0.f;
    }
    sl[threadIdx.x] = bl;
    sa[threadIdx.x] = fl;
    __syncthreads();
    for (int off = 256; off; off >>= 1) {
        if (threadIdx.x < off) {
            sl[threadIdx.x] += sl[threadIdx.x + off];
            sa[threadIdx.x] += sa[threadIdx.x + off];
        }
        __syncthreads();
    }
    if (threadIdx.x == 0) {
        out[0] = sl[0] / (float)NQ;
        out[1] = sa[0] / (float)NQ;
    }
}

extern "C" void kernel_launch(void* const* d_in, const int* in_sizes, int n_in,
                              void* d_out, int out_size, void* d_ws, size_t ws_size,
                              hipStream_t stream) {
    const float* inp = (const float*)d_in[0];
    const int* target = (const int*)d_in[1];
    float* out = (float*)d_out;
    char* ws = (char*)d_ws;

    size_t off = 0;
    auto carve = [&](size_t bytes) {
        void* p = ws + off;
        off = (off + bytes + 255) & ~(size_t)255;
        return p;
    };
    int* order = (int*)carve(NTOT * sizeof(int));
    int* qsrc = (int*)carve(NQ * sizeof(int));
    float* proto = (float*)carve((size_t)NCLASS * T * C * sizeof(float));   // 5.24 MB
    float* x2 = (float*)carve((size_t)NQROWS * sizeof(float));
    float* y2 = (float*)carve((size_t)NPROWS * sizeof(float));
    float* xy = (float*)carve((size_t)NQROWS * NPROWS * sizeof(float));     // 40.96 MB
    float* gxx = (float*)carve((size_t)NQ * T * T * sizeof(float));         // 2.05 MB
    float* gyy = (float*)carve((size_t)NCLASS * T * T * sizeof(float));
    float* dxy = (float*)carve((size_t)NQ * NCLASS * sizeof(float));
    float* dxx = (float*)carve((size_t)NQ * sizeof(float));
    float* dyy = (float*)carve((size_t)NCLASS * sizeof(float));
    (void)ws_size;  // total ~48.5 MB

    sort_kernel<<<1, 64, 0, stream>>>(target, order, qsrc);
    proto_kernel<<<(NCLASS * T * C) / 256, 256, 0, stream>>>(inp, order, proto);
    rownorm_q_kernel<<<NQROWS / 4, 256, 0, stream>>>(inp, qsrc, x2);
    rownorm_p_kernel<<<NPROWS / 4, 256, 0, stream>>>(proto, y2);
    gemm_xy_kernel<<<dim3(NQROWS / 64, NPROWS / 64), 256, 0, stream>>>(inp, proto, qsrc, xy);
    syrk_kernel<<<NQ, 256, 0, stream>>>(inp, qsrc, gxx, 0);
    syrk_kernel<<<NCLASS, 256, 0, stream>>>(proto, qsrc, gyy, 1);
    softdtw_kernel<<<(NQ * NCLASS + 63) / 64, 64, 0, stream>>>(xy, x2, y2, dxy, 0, NQ * NCLASS);
    softdtw_kernel<<<(NQ + 63) / 64, 64, 0, stream>>>(gxx, x2, x2, dxx, 1, NQ);
    softdtw_kernel<<<1, 64, 0, stream>>>(gyy, y2, y2, dyy, 1, NCLASS);
    finalize_kernel<<<1, 512, 0, stream>>>(dxy, dxx, dyy, out);
}

// Round 2
// 474.682 us; speedup vs baseline: 2.2292x; 2.2292x over previous
//
#include <hip/hip_runtime.h>

#define T 32
#define C 2048
#define NTOT 600
#define NCLASS 20
#define NSUP 5
#define PER 30
#define NQPC 25
#define NQ 500
#define NQROWS (NQ * T)      // 16000
#define NPROWS (NCLASS * T)  // 640
#define GAMMA 0.1f
#define INVG 10.0f
#define BIG 1e10f
#define NMM (NQ * NCLASS + NQ + NCLASS)  // 10520

typedef short bf16x8 __attribute__((ext_vector_type(8)));
typedef float f32x4 __attribute__((ext_vector_type(4)));

__device__ __forceinline__ void gload16(const void* g, void* l) {
    __builtin_amdgcn_global_load_lds((const __attribute__((address_space(1))) void*)g,
                                     (__attribute__((address_space(3))) void*)l, 16, 0, 0);
}

__device__ __forceinline__ unsigned bf16_rne(float f) {
    unsigned u = __float_as_uint(f);
    return (u + 0x7fffu + ((u >> 16) & 1u)) >> 16;
}

// ---------------- stable counting sort + query source indices ----------------
__global__ void sort_kernel(const int* __restrict__ target, int* __restrict__ order,
                            int* __restrict__ qsrc) {
    if (blockIdx.x != 0 || threadIdx.x != 0) return;
    int cnt[NCLASS];
    for (int c = 0; c < NCLASS; c++) cnt[c] = 0;
    for (int i = 0; i < NTOT; i++) cnt[target[i]]++;
    int off[NCLASS];
    int run = 0;
    for (int c = 0; c < NCLASS; c++) { off[c] = run; run += cnt[c]; }
    for (int i = 0; i < NTOT; i++) { int c = target[i]; order[off[c]++] = i; }
    for (int q = 0; q < NQ; q++) {
        int cls = q / NQPC, w = q % NQPC;
        qsrc[q] = order[cls * PER + NSUP + w];
    }
}

// ---------------- prototypes: mean over support ----------------
__global__ void proto_kernel(const float* __restrict__ inp, const int* __restrict__ order,
                             float* __restrict__ proto) {
    int idx = blockIdx.x * 256 + threadIdx.x;
    int cls = idx / (T * C);
    int rem = idx % (T * C);
    float s = 0.f;
#pragma unroll
    for (int sup = 0; sup < NSUP; sup++) {
        int src = order[cls * PER + sup];
        s += inp[(size_t)src * (T * C) + rem];
    }
    proto[idx] = s / 5.0f;
}

// ---------------- squared row norms (wave per row) ----------------
__global__ void rownorm_q_kernel(const float* __restrict__ inp, const int* __restrict__ qsrc,
                                 float* __restrict__ x2) {
    int w = (int)((blockIdx.x * (size_t)blockDim.x + threadIdx.x) >> 6);
    int lane = threadIdx.x & 63;
    if (w >= NQROWS) return;
    int q = w >> 5, i = w & 31;
    const float* p = inp + (size_t)qsrc[q] * (T * C) + (size_t)i * C;
    float s = 0.f;
#pragma unroll
    for (int k0 = 0; k0 < C; k0 += 256) {
        float4 v = *(const float4*)(p + k0 + lane * 4);
        s += v.x * v.x + v.y * v.y + v.z * v.z + v.w * v.w;
    }
#pragma unroll
    for (int off = 32; off; off >>= 1) s += __shfl_xor(s, off);
    if (lane == 0) x2[w] = s;
}

__global__ void rownorm_p_kernel(const float* __restrict__ proto, float* __restrict__ y2) {
    int w = (int)((blockIdx.x * (size_t)blockDim.x + threadIdx.x) >> 6);
    int lane = threadIdx.x & 63;
    if (w >= NPROWS) return;
    const float* p = proto + (size_t)w * C;
    float s = 0.f;
#pragma unroll
    for (int k0 = 0; k0 < C; k0 += 256) {
        float4 v = *(const float4*)(p + k0 + lane * 4);
        s += v.x * v.x + v.y * v.y + v.z * v.z + v.w * v.w;
    }
#pragma unroll
    for (int off = 32; off; off >>= 1) s += __shfl_xor(s, off);
    if (lane == 0) y2[w] = s;
}

// ---------------- f32 -> (bf16 hi, bf16 lo) split, chunk-transposed staged layout ----
// dst layout: [K/8][nrows][8] bf16 (bf16x8 element index = kchunk*nrows + row)
__global__ __launch_bounds__(256) void conv_split_kernel(const float* __restrict__ src,
                                                         const int* __restrict__ qsrc,
                                                         int gather, int nrows,
                                                         bf16x8* __restrict__ dhi,
                                                         bf16x8* __restrict__ dlo) {
    __shared__ __align__(16) short lh[8][64][8];
    __shared__ __align__(16) short ll[8][64][8];
    int tid = threadIdx.x;
    int m0 = blockIdx.x * 64, k0 = blockIdx.y * 64;
    int r = tid >> 2, kc = (tid & 3) << 4;
    int m = m0 + r;
    const float* rowp;
    if (gather) {
        int q = m >> 5;
        rowp = src + (size_t)qsrc[q] * (T * C) + (size_t)(m & 31) * C;
    } else {
        rowp = src + (size_t)m * C;
    }
    float4 v0 = *(const float4*)(rowp + k0 + kc + 0);
    float4 v1 = *(const float4*)(rowp + k0 + kc + 4);
    float4 v2 = *(const float4*)(rowp + k0 + kc + 8);
    float4 v3 = *(const float4*)(rowp + k0 + kc + 12);
    float vals[16];
    vals[0] = v0.x; vals[1] = v0.y; vals[2] = v0.z; vals[3] = v0.w;
    vals[4] = v1.x; vals[5] = v1.y; vals[6] = v1.z; vals[7] = v1.w;
    vals[8] = v2.x; vals[9] = v2.y; vals[10] = v2.z; vals[11] = v2.w;
    vals[12] = v3.x; vals[13] = v3.y; vals[14] = v3.z; vals[15] = v3.w;
#pragma unroll
    for (int e = 0; e < 16; e++) {
        float f = vals[e];
        unsigned hb = bf16_rne(f);
        float hf = __uint_as_float(hb << 16);
        float lof = f - hf;
        unsigned lb = bf16_rne(lof);
        int cc = (kc + e) >> 3, j = (kc + e) & 7;
        lh[cc][r][j] = (short)hb;
        ll[cc][r][j] = (short)lb;
    }
    __syncthreads();
#pragma unroll
    for (int w = 0; w < 2; w++) {
        int idx = w * 256 + tid;
        int cc = idx >> 6, r2 = idx & 63;
        size_t o = (size_t)(k0 / 8 + cc) * nrows + m0 + r2;
        dhi[o] = *(const bf16x8*)&lh[cc][r2][0];
        dlo[o] = *(const bf16x8*)&ll[cc][r2][0];
    }
}

// ---------------- split-bf16 MFMA GEMM: xy[16000][640] ----------------
__global__ __launch_bounds__(256) void gemm_mfma_kernel(const bf16x8* __restrict__ Ah,
                                                        const bf16x8* __restrict__ Al,
                                                        const bf16x8* __restrict__ Bh,
                                                        const bf16x8* __restrict__ Bl,
                                                        float* __restrict__ xy) {
    __shared__ bf16x8 sAh[512], sAl[512], sBh[512], sBl[512];  // 4 x 8KB
    int tid = threadIdx.x, lane = tid & 63, wid = tid >> 6;
    int wr = wid >> 1, wc = wid & 1;
    int m0 = blockIdx.x * 128, n0 = blockIdx.y * 128;
    int i0 = tid, i1 = tid + 256;
    const bf16x8* gAh0 = Ah + (size_t)(i0 >> 7) * NQROWS + m0 + (i0 & 127);
    const bf16x8* gAh1 = Ah + (size_t)(i1 >> 7) * NQROWS + m0 + (i1 & 127);
    const bf16x8* gAl0 = Al + (size_t)(i0 >> 7) * NQROWS + m0 + (i0 & 127);
    const bf16x8* gAl1 = Al + (size_t)(i1 >> 7) * NQROWS + m0 + (i1 & 127);
    const bf16x8* gBh0 = Bh + (size_t)(i0 >> 7) * NPROWS + n0 + (i0 & 127);
    const bf16x8* gBh1 = Bh + (size_t)(i1 >> 7) * NPROWS + n0 + (i1 & 127);
    const bf16x8* gBl0 = Bl + (size_t)(i0 >> 7) * NPROWS + n0 + (i0 & 127);
    const bf16x8* gBl1 = Bl + (size_t)(i1 >> 7) * NPROWS + n0 + (i1 & 127);
    f32x4 acc[4][4];
    f32x4 zero = {0.f, 0.f, 0.f, 0.f};
#pragma unroll
    for (int mi = 0; mi < 4; mi++)
#pragma unroll
        for (int ni = 0; ni < 4; ni++) acc[mi][ni] = zero;
    int g = lane >> 4, r = lane & 15;
    int aoff = g * 128 + wr * 64 + r;
    int boff = g * 128 + wc * 64 + r;
    for (int t = 0; t < C / 32; t++) {
        gload16(gAh0, &sAh[i0]); gload16(gAh1, &sAh[i1]);
        gload16(gAl0, &sAl[i0]); gload16(gAl1, &sAl[i1]);
        gload16(gBh0, &sBh[i0]); gload16(gBh1, &sBh[i1]);
        gload16(gBl0, &sBl[i0]); gload16(gBl1, &sBl[i1]);
        gAh0 += 4 * NQROWS; gAh1 += 4 * NQROWS; gAl0 += 4 * NQROWS; gAl1 += 4 * NQROWS;
        gBh0 += 4 * NPROWS; gBh1 += 4 * NPROWS; gBl0 += 4 * NPROWS; gBl1 += 4 * NPROWS;
        __syncthreads();
        bf16x8 ah[4], al[4], bh[4], bl[4];
#pragma unroll
        for (int i = 0; i < 4; i++) {
            ah[i] = sAh[aoff + i * 16];
            al[i] = sAl[aoff + i * 16];
            bh[i] = sBh[boff + i * 16];
            bl[i] = sBl[boff + i * 16];
        }
#pragma unroll
        for (int mi = 0; mi < 4; mi++)
#pragma unroll
            for (int ni = 0; ni < 4; ni++) {
                acc[mi][ni] = __builtin_amdgcn_mfma_f32_16x16x32_bf16(ah[mi], bh[ni], acc[mi][ni], 0, 0, 0);
                acc[mi][ni] = __builtin_amdgcn_mfma_f32_16x16x32_bf16(ah[mi], bl[ni], acc[mi][ni], 0, 0, 0);
                acc[mi][ni] = __builtin_amdgcn_mfma_f32_16x16x32_bf16(al[mi], bh[ni], acc[mi][ni], 0, 0, 0);
            }
        __syncthreads();
    }
    int orow = m0 + wr * 64 + (lane >> 4) * 4;
    int ocol = n0 + wc * 64 + (lane & 15);
#pragma unroll
    for (int mi = 0; mi < 4; mi++)
#pragma unroll
        for (int ni = 0; ni < 4; ni++)
#pragma unroll
            for (int j = 0; j < 4; j++)
                xy[(size_t)(orow + mi * 16 + j) * NPROWS + ocol + ni * 16] = acc[mi][ni][j];
}

// ---------------- fallback fp32 vector GEMM (if ws too small) ----------------
__global__ __launch_bounds__(256) void gemm_xy_kernel(const float* __restrict__ inp,
                                                      const float* __restrict__ proto,
                                                      const int* __restrict__ qsrc,
                                                      float* __restrict__ xy) {
    __shared__ float As[16][64];
    __shared__ float Bs[16][64];
    __shared__ int arow[64];
    int tid = threadIdx.x;
    int bm = blockIdx.x, bn = blockIdx.y;
    if (tid < 64) {
        int rr = bm * 64 + tid;
        arow[tid] = qsrc[rr >> 5] * (T * C) + (rr & 31) * C;
    }
    __syncthreads();
    int lr = tid >> 2;
    int lk = (tid & 3) << 2;
    int tm = (tid >> 4) << 2;
    int tn = (tid & 15) << 2;
    int aoff = arow[lr];
    const float* brow = proto + (size_t)(bn * 64 + lr) * C;
    float acc[4][4] = {};
    for (int k0 = 0; k0 < C; k0 += 16) {
        float4 av = *(const float4*)(inp + (size_t)aoff + k0 + lk);
        float4 bv = *(const float4*)(brow + k0 + lk);
        __syncthreads();
        As[lk + 0][lr] = av.x; As[lk + 1][lr] = av.y; As[lk + 2][lr] = av.z; As[lk + 3][lr] = av.w;
        Bs[lk + 0][lr] = bv.x; Bs[lk + 1][lr] = bv.y; Bs[lk + 2][lr] = bv.z; Bs[lk + 3][lr] = bv.w;
        __syncthreads();
#pragma unroll
        for (int k = 0; k < 16; k++) {
            float4 a = *(const float4*)&As[k][tm];
            float4 b = *(const float4*)&Bs[k][tn];
            acc[0][0] += a.x * b.x; acc[0][1] += a.x * b.y; acc[0][2] += a.x * b.z; acc[0][3] += a.x * b.w;
            acc[1][0] += a.y * b.x; acc[1][1] += a.y * b.y; acc[1][2] += a.y * b.z; acc[1][3] += a.y * b.w;
            acc[2][0] += a.z * b.x; acc[2][1] += a.z * b.y; acc[2][2] += a.z * b.z; acc[2][3] += a.z * b.w;
            acc[3][0] += a.w * b.x; acc[3][1] += a.w * b.y; acc[3][2] += a.w * b.z; acc[3][3] += a.w * b.w;
        }
    }
#pragma unroll
    for (int ii = 0; ii < 4; ii++) {
        int rr = bm * 64 + tm + ii;
        float4 o = make_float4(acc[ii][0], acc[ii][1], acc[ii][2], acc[ii][3]);
        *(float4*)&xy[(size_t)rr * NPROWS + bn * 64 + tn] = o;
    }
}

// ---------------- batched SYRK: G[mat] = A A^T for 32x2048 A ----------------
__global__ __launch_bounds__(256) void syrk_kernel(const float* __restrict__ srcbase,
                                                   const int* __restrict__ qsrc,
                                                   float* __restrict__ gout, int mode) {
    int mat = blockIdx.x;
    const float* src = (mode == 0) ? srcbase + (size_t)qsrc[mat] * (T * C)
                                   : srcbase + (size_t)mat * (T * C);
    __shared__ float As[64][32];
    int tid = threadIdx.x;
    int row = tid >> 3;
    int kof = (tid & 7) * 8;
    int j4 = (tid & 7) * 4;
    float acc[4] = {};
    for (int k0 = 0; k0 < C; k0 += 64) {
        float4 v0 = *(const float4*)(src + (size_t)row * C + k0 + kof);
        float4 v1 = *(const float4*)(src + (size_t)row * C + k0 + kof + 4);
        __syncthreads();
        As[kof + 0][row] = v0.x; As[kof + 1][row] = v0.y; As[kof + 2][row] = v0.z; As[kof + 3][row] = v0.w;
        As[kof + 4][row] = v1.x; As[kof + 5][row] = v1.y; As[kof + 6][row] = v1.z; As[kof + 7][row] = v1.w;
        __syncthreads();
#pragma unroll
        for (int k = 0; k < 64; k++) {
            float a = As[k][row];
            float4 b = *(const float4*)&As[k][j4];
            acc[0] += a * b.x; acc[1] += a * b.y; acc[2] += a * b.z; acc[3] += a * b.w;
        }
    }
    float* o = gout + (size_t)mat * (T * T) + row * T + j4;
    o[0] = acc[0]; o[1] = acc[1]; o[2] = acc[2]; o[3] = acc[3];
}

// ---------------- merged soft-DTW DP: one thread per 32x32 cost matrix ----------------
__global__ void softdtw_all_kernel(const float* __restrict__ xy, const float* __restrict__ gxx,
                                   const float* __restrict__ gyy, const float* __restrict__ x2,
                                   const float* __restrict__ y2, float* __restrict__ dxy,
                                   float* __restrict__ dxx, float* __restrict__ dyy) {
    int mm = blockIdx.x * 64 + threadIdx.x;
    if (mm >= NMM) return;
    const float* rterm;
    const float* cterm;
    const float* cptr;
    int cstride;
    float* outp;
    if (mm < NQ * NCLASS) {
        int q = mm / NCLASS, m = mm % NCLASS;
        rterm = x2 + q * T;
        cterm = y2 + m * T;
        cptr = xy + (size_t)(q * T) * NPROWS + m * T;
        cstride = NPROWS;
        outp = dxy + mm;
    } else if (mm < NQ * NCLASS + NQ) {
        int i = mm - NQ * NCLASS;
        rterm = x2 + i * T;
        cterm = rterm;
        cptr = gxx + (size_t)i * (T * T);
        cstride = T;
        outp = dxx + i;
    } else {
        int i = mm - NQ * NCLASS - NQ;
        rterm = y2 + i * T;
        cterm = rterm;
        cptr = gyy + (size_t)i * (T * T);
        cstride = T;
        outp = dyy + i;
    }
    float cj[T];
#pragma unroll
    for (int j = 0; j < T; j++) cj[j] = cterm[j];
    float Rp[T + 1];
    Rp[0] = 0.f;
#pragma unroll
    for (int j = 1; j <= T; j++) Rp[j] = BIG;
    for (int i = 0; i < T; i++) {
        float diag = Rp[0];
        Rp[0] = BIG;
        float left = BIG;
        float ai = rterm[i];
        const float4* crow4 = (const float4*)(cptr + (size_t)i * cstride);
        float cr[T];
#pragma unroll
        for (int jj = 0; jj < 8; jj++) {
            float4 v = crow4[jj];
            cr[jj * 4 + 0] = v.x; cr[jj * 4 + 1] = v.y;
            cr[jj * 4 + 2] = v.z; cr[jj * 4 + 3] = v.w;
        }
#pragma unroll
        for (int j = 0; j < T; j++) {
            float up = Rp[j + 1];
            float d = ai + cj[j] - 2.0f * cr[j];
            float mn = fminf(diag, fminf(up, left));
            float ssum = __expf((mn - diag) * INVG) + __expf((mn - up) * INVG) +
                         __expf((mn - left) * INVG);
            float rr = d + mn - GAMMA * __logf(ssum);
            diag = up;
            Rp[j + 1] = rr;
            left = rr;
        }
    }
    *outp = Rp[T];
}

// ---------------- finalize: dist, log-softmax, loss, acc ----------------
__global__ __launch_bounds__(512) void finalize_kernel(const float* __restrict__ dxy,
                                                       const float* __restrict__ dxx,
                                                       const float* __restrict__ dyy,
                                                       float* __restrict__ out) {
    __shared__ float sl[512];
    __shared__ float sa[512];
    int q = threadIdx.x;
    float bl = 0.f, fl = 0.f;
    if (q < NQ) {
        float dxxq = dxx[q];
        int cq = q / NQPC;
        float dd[NCLASS];
#pragma unroll
        for (int m = 0; m < NCLASS; m++)
            dd[m] = dxy[q * NCLASS + m] - 0.5f * (dxxq + dyy[m]);
        float best = dd[0];
        int bi = 0;
#pragma unroll
        for (int m = 1; m < NCLASS; m++) {
            if (dd[m] < best) { best = dd[m]; bi = m; }
        }
        float s = 0.f;
        float dcq = dd[0];
#pragma unroll
        for (int m = 0; m < NCLASS; m++) {
            s += __expf(best - dd[m]);
            if (m == cq) dcq = dd[m];
        }
        float lse = __logf(s) - best;
        bl = dcq + lse;
        out[2 + q] = bl;
        fl = (bi == cq) ? 1.f : 0.f;
    }
    sl[threadIdx.x] = bl;
    sa[threadIdx.x] = fl;
    __syncthreads();
    for (int off = 256; off; off >>= 1) {
        if (threadIdx.x < off) {
            sl[threadIdx.x] += sl[threadIdx.x + off];
            sa[threadIdx.x] += sa[threadIdx.x + off];
        }
        __syncthreads();
    }
    if (threadIdx.x == 0) {
        out[0] = sl[0] / (float)NQ;
        out[1] = sa[0] / (float)NQ;
    }
}

extern "C" void kernel_launch(void* const* d_in, const int* in_sizes, int n_in,
                              void* d_out, int out_size, void* d_ws, size_t ws_size,
                              hipStream_t stream) {
    const float* inp = (const float*)d_in[0];
    const int* target = (const int*)d_in[1];
    float* out = (float*)d_out;
    char* ws = (char*)d_ws;

    size_t off = 0;
    auto carve = [&](size_t bytes) {
        void* p = ws + off;
        off = (off + bytes + 255) & ~(size_t)255;
        return p;
    };
    int* order = (int*)carve(NTOT * sizeof(int));
    int* qsrc = (int*)carve(NQ * sizeof(int));
    float* proto = (float*)carve((size_t)NCLASS * T * C * sizeof(float));
    float* x2 = (float*)carve((size_t)NQROWS * sizeof(float));
    float* y2 = (float*)carve((size_t)NPROWS * sizeof(float));
    float* xy = (float*)carve((size_t)NQROWS * NPROWS * sizeof(float));
    float* gxx = (float*)carve((size_t)NQ * T * T * sizeof(float));
    float* gyy = (float*)carve((size_t)NCLASS * T * T * sizeof(float));
    float* dxy = (float*)carve((size_t)NQ * NCLASS * sizeof(float));
    float* dxx = (float*)carve((size_t)NQ * sizeof(float));
    float* dyy = (float*)carve((size_t)NCLASS * sizeof(float));
    // staged split-bf16 operands, layout [K/8][nrows] of bf16x8
    bf16x8* Ah = (bf16x8*)carve((size_t)(C / 8) * NQROWS * 16);
    bf16x8* Al = (bf16x8*)carve((size_t)(C / 8) * NQROWS * 16);
    bf16x8* Bh = (bf16x8*)carve((size_t)(C / 8) * NPROWS * 16);
    bf16x8* Bl = (bf16x8*)carve((size_t)(C / 8) * NPROWS * 16);
    bool mfma_ok = (off <= ws_size);

    sort_kernel<<<1, 64, 0, stream>>>(target, order, qsrc);
    proto_kernel<<<(NCLASS * T * C) / 256, 256, 0, stream>>>(inp, order, proto);
    rownorm_q_kernel<<<NQROWS / 4, 256, 0, stream>>>(inp, qsrc, x2);
    rownorm_p_kernel<<<NPROWS / 4, 256, 0, stream>>>(proto, y2);
    if (mfma_ok) {
        conv_split_kernel<<<dim3(NQROWS / 64, C / 64), 256, 0, stream>>>(inp, qsrc, 1, NQROWS, Ah, Al);
        conv_split_kernel<<<dim3(NPROWS / 64, C / 64), 256, 0, stream>>>(proto, qsrc, 0, NPROWS, Bh, Bl);
        gemm_mfma_kernel<<<dim3(NQROWS / 128, NPROWS / 128), 256, 0, stream>>>(Ah, Al, Bh, Bl, xy);
    } else {
        gemm_xy_kernel<<<dim3(NQROWS / 64, NPROWS / 64), 256, 0, stream>>>(inp, proto, qsrc, xy);
    }
    syrk_kernel<<<NQ, 256, 0, stream>>>(inp, qsrc, gxx, 0);
    syrk_kernel<<<NCLASS, 256, 0, stream>>>(proto, qsrc, gyy, 1);
    softdtw_all_kernel<<<(NMM + 63) / 64, 64, 0, stream>>>(xy, gxx, gyy, x2, y2, dxy, dxx, dyy);
    finalize_kernel<<<1, 512, 0, stream>>>(dxy, dxx, dyy, out);
}

// Round 3
// 339.690 us; speedup vs baseline: 3.1150x; 1.3974x over previous
//
#include <hip/hip_runtime.h>

#define T 32
#define C 2048
#define NTOT 600
#define NCLASS 20
#define NSUP 5
#define PER 30
#define NQPC 25
#define NQ 500
#define NQROWS (NQ * T)      // 16000
#define NPROWS (NCLASS * T)  // 640
#define GAMMA 0.1f
#define INVG 10.0f
#define BIG 1e10f
#define NMM (NQ * NCLASS + NQ + NCLASS)  // 10520

typedef short bf16x8 __attribute__((ext_vector_type(8)));
typedef float f32x4 __attribute__((ext_vector_type(4)));

__device__ __forceinline__ void gload16(const void* g, void* l) {
    __builtin_amdgcn_global_load_lds((const __attribute__((address_space(1))) void*)g,
                                     (__attribute__((address_space(3))) void*)l, 16, 0, 0);
}

__device__ __forceinline__ unsigned bf16_rne(float f) {
    unsigned u = __float_as_uint(f);
    return (u + 0x7fffu + ((u >> 16) & 1u)) >> 16;
}

// ---------------- parallel stable counting sort (1 block) ----------------
__global__ __launch_bounds__(640) void sort_kernel(const int* __restrict__ target,
                                                   int* __restrict__ order,
                                                   int* __restrict__ qsrc) {
    __shared__ int tgt[NTOT];
    __shared__ int offs[NCLASS];
    __shared__ int ordl[NTOT];
    int tid = threadIdx.x;
    if (tid < NTOT) tgt[tid] = target[tid];
    __syncthreads();
    if (tid < NCLASS) {
        int o = 0;
        for (int i = 0; i < NTOT; i++) o += (tgt[i] < tid) ? 1 : 0;
        offs[tid] = o;  // exclusive prefix = start of class tid
    }
    __syncthreads();
    if (tid < NTOT) {
        int c = tgt[tid];
        int rank = 0;
        for (int k = 0; k < NTOT; k++) rank += (k < tid && tgt[k] == c) ? 1 : 0;
        ordl[offs[c] + rank] = tid;
    }
    __syncthreads();
    if (tid < NTOT) order[tid] = ordl[tid];
    if (tid < NQ) qsrc[tid] = ordl[(tid / NQPC) * PER + NSUP + (tid % NQPC)];
}

// ---------------- stage A: gather + f32->(bf16 hi,lo) split + row norms ----------------
// staged layout: [K/8][nrows] of bf16x8
__global__ __launch_bounds__(256) void stage_a_kernel(const float* __restrict__ inp,
                                                      const int* __restrict__ qsrc,
                                                      bf16x8* __restrict__ dhi,
                                                      bf16x8* __restrict__ dlo,
                                                      float* __restrict__ x2) {
    int tid = threadIdx.x;
    int r = tid >> 4, p = tid & 15;
    int m = blockIdx.x * 16 + r;
    const float* src = inp + (size_t)qsrc[m >> 5] * (T * C) + (size_t)(m & 31) * C;
    float sumsq = 0.f;
#pragma unroll
    for (int s = 0; s < 8; s++) {
        int col = s * 256 + p * 16;
        float4 v0 = *(const float4*)(src + col + 0);
        float4 v1 = *(const float4*)(src + col + 4);
        float4 v2 = *(const float4*)(src + col + 8);
        float4 v3 = *(const float4*)(src + col + 12);
        float vals[16];
        vals[0] = v0.x; vals[1] = v0.y; vals[2] = v0.z; vals[3] = v0.w;
        vals[4] = v1.x; vals[5] = v1.y; vals[6] = v1.z; vals[7] = v1.w;
        vals[8] = v2.x; vals[9] = v2.y; vals[10] = v2.z; vals[11] = v2.w;
        vals[12] = v3.x; vals[13] = v3.y; vals[14] = v3.z; vals[15] = v3.w;
        bf16x8 hv0, hv1, lv0, lv1;
#pragma unroll
        for (int e = 0; e < 8; e++) {
            float f = vals[e];
            sumsq += f * f;
            unsigned hb = bf16_rne(f);
            float lof = f - __uint_as_float(hb << 16);
            hv0[e] = (short)hb;
            lv0[e] = (short)bf16_rne(lof);
        }
#pragma unroll
        for (int e = 0; e < 8; e++) {
            float f = vals[8 + e];
            sumsq += f * f;
            unsigned hb = bf16_rne(f);
            float lof = f - __uint_as_float(hb << 16);
            hv1[e] = (short)hb;
            lv1[e] = (short)bf16_rne(lof);
        }
        size_t base = (size_t)(s * 32 + p * 2) * NQROWS + m;
        dhi[base] = hv0; dhi[base + NQROWS] = hv1;
        dlo[base] = lv0; dlo[base + NQROWS] = lv1;
    }
#pragma unroll
    for (int d = 1; d < 16; d <<= 1) sumsq += __shfl_xor(sumsq, d);
    if (p == 0) x2[m] = sumsq;
}

// ---------------- stage B: proto mean + split + row norms ----------------
__global__ __launch_bounds__(256) void stage_b_kernel(const float* __restrict__ inp,
                                                      const int* __restrict__ order,
                                                      bf16x8* __restrict__ dhi,
                                                      bf16x8* __restrict__ dlo,
                                                      float* __restrict__ y2) {
    int tid = threadIdx.x;
    int r = tid >> 4, p = tid & 15;
    int m = blockIdx.x * 16 + r;  // proto row 0..639
    int cls = m >> 5, trow = m & 31;
    const float* s0 = inp + (size_t)order[cls * PER + 0] * (T * C) + (size_t)trow * C;
    const float* s1 = inp + (size_t)order[cls * PER + 1] * (T * C) + (size_t)trow * C;
    const float* s2 = inp + (size_t)order[cls * PER + 2] * (T * C) + (size_t)trow * C;
    const float* s3 = inp + (size_t)order[cls * PER + 3] * (T * C) + (size_t)trow * C;
    const float* s4 = inp + (size_t)order[cls * PER + 4] * (T * C) + (size_t)trow * C;
    float sumsq = 0.f;
#pragma unroll
    for (int s = 0; s < 8; s++) {
        int col = s * 256 + p * 16;
        float vals[16];
#pragma unroll
        for (int c4 = 0; c4 < 4; c4++) {
            float4 a = *(const float4*)(s0 + col + c4 * 4);
            float4 b = *(const float4*)(s1 + col + c4 * 4);
            float4 c = *(const float4*)(s2 + col + c4 * 4);
            float4 d = *(const float4*)(s3 + col + c4 * 4);
            float4 e = *(const float4*)(s4 + col + c4 * 4);
            vals[c4 * 4 + 0] = (a.x + b.x + c.x + d.x + e.x) * 0.2f;
            vals[c4 * 4 + 1] = (a.y + b.y + c.y + d.y + e.y) * 0.2f;
            vals[c4 * 4 + 2] = (a.z + b.z + c.z + d.z + e.z) * 0.2f;
            vals[c4 * 4 + 3] = (a.w + b.w + c.w + d.w + e.w) * 0.2f;
        }
        bf16x8 hv0, hv1, lv0, lv1;
#pragma unroll
        for (int e = 0; e < 8; e++) {
            float f = vals[e];
            sumsq += f * f;
            unsigned hb = bf16_rne(f);
            float lof = f - __uint_as_float(hb << 16);
            hv0[e] = (short)hb;
            lv0[e] = (short)bf16_rne(lof);
        }
#pragma unroll
        for (int e = 0; e < 8; e++) {
            float f = vals[8 + e];
            sumsq += f * f;
            unsigned hb = bf16_rne(f);
            float lof = f - __uint_as_float(hb << 16);
            hv1[e] = (short)hb;
            lv1[e] = (short)bf16_rne(lof);
        }
        size_t base = (size_t)(s * 32 + p * 2) * NPROWS + m;
        dhi[base] = hv0; dhi[base + NPROWS] = hv1;
        dlo[base] = lv0; dlo[base + NPROWS] = lv1;
    }
#pragma unroll
    for (int d = 1; d < 16; d <<= 1) sumsq += __shfl_xor(sumsq, d);
    if (p == 0) y2[m] = sumsq;
}

// ---------------- split-bf16 MFMA GEMM: xy[16000][640], XCD-swizzled ----------------
__global__ __launch_bounds__(256) void gemm_mfma_kernel(const bf16x8* __restrict__ Ah,
                                                        const bf16x8* __restrict__ Al,
                                                        const bf16x8* __restrict__ Bh,
                                                        const bf16x8* __restrict__ Bl,
                                                        float* __restrict__ xy) {
    // bijective XCD swizzle: 625 blocks = 8*78+1; same-bm groups land on one XCD
    int o = blockIdx.x;
    int xcd = o & 7, slot = o >> 3;
    int v = (xcd < 1 ? xcd * 79 : 79 + (xcd - 1) * 78) + slot;
    int bm = v / 5, bn = v % 5;
    __shared__ bf16x8 sAh[512], sAl[512], sBh[512], sBl[512];  // 4 x 8KB
    int tid = threadIdx.x, lane = tid & 63, wid = tid >> 6;
    int wr = wid >> 1, wc = wid & 1;
    int m0 = bm * 128, n0 = bn * 128;
    int i0 = tid, i1 = tid + 256;
    const bf16x8* gAh0 = Ah + (size_t)(i0 >> 7) * NQROWS + m0 + (i0 & 127);
    const bf16x8* gAh1 = Ah + (size_t)(i1 >> 7) * NQROWS + m0 + (i1 & 127);
    const bf16x8* gAl0 = Al + (size_t)(i0 >> 7) * NQROWS + m0 + (i0 & 127);
    const bf16x8* gAl1 = Al + (size_t)(i1 >> 7) * NQROWS + m0 + (i1 & 127);
    const bf16x8* gBh0 = Bh + (size_t)(i0 >> 7) * NPROWS + n0 + (i0 & 127);
    const bf16x8* gBh1 = Bh + (size_t)(i1 >> 7) * NPROWS + n0 + (i1 & 127);
    const bf16x8* gBl0 = Bl + (size_t)(i0 >> 7) * NPROWS + n0 + (i0 & 127);
    const bf16x8* gBl1 = Bl + (size_t)(i1 >> 7) * NPROWS + n0 + (i1 & 127);
    f32x4 acc[4][4];
    f32x4 zero = {0.f, 0.f, 0.f, 0.f};
#pragma unroll
    for (int mi = 0; mi < 4; mi++)
#pragma unroll
        for (int ni = 0; ni < 4; ni++) acc[mi][ni] = zero;
    int g = lane >> 4, r = lane & 15;
    int aoff = g * 128 + wr * 64 + r;
    int boff = g * 128 + wc * 64 + r;
    for (int t = 0; t < C / 32; t++) {
        gload16(gAh0, &sAh[i0]); gload16(gAh1, &sAh[i1]);
        gload16(gAl0, &sAl[i0]); gload16(gAl1, &sAl[i1]);
        gload16(gBh0, &sBh[i0]); gload16(gBh1, &sBh[i1]);
        gload16(gBl0, &sBl[i0]); gload16(gBl1, &sBl[i1]);
        gAh0 += 4 * NQROWS; gAh1 += 4 * NQROWS; gAl0 += 4 * NQROWS; gAl1 += 4 * NQROWS;
        gBh0 += 4 * NPROWS; gBh1 += 4 * NPROWS; gBl0 += 4 * NPROWS; gBl1 += 4 * NPROWS;
        __syncthreads();
        bf16x8 ah[4], al[4], bh[4], bl[4];
#pragma unroll
        for (int i = 0; i < 4; i++) {
            ah[i] = sAh[aoff + i * 16];
            al[i] = sAl[aoff + i * 16];
            bh[i] = sBh[boff + i * 16];
            bl[i] = sBl[boff + i * 16];
        }
#pragma unroll
        for (int mi = 0; mi < 4; mi++)
#pragma unroll
            for (int ni = 0; ni < 4; ni++) {
                acc[mi][ni] = __builtin_amdgcn_mfma_f32_16x16x32_bf16(ah[mi], bh[ni], acc[mi][ni], 0, 0, 0);
                acc[mi][ni] = __builtin_amdgcn_mfma_f32_16x16x32_bf16(ah[mi], bl[ni], acc[mi][ni], 0, 0, 0);
                acc[mi][ni] = __builtin_amdgcn_mfma_f32_16x16x32_bf16(al[mi], bh[ni], acc[mi][ni], 0, 0, 0);
            }
        __syncthreads();
    }
    int orow = m0 + wr * 64 + (lane >> 4) * 4;
    int ocol = n0 + wc * 64 + (lane & 15);
#pragma unroll
    for (int mi = 0; mi < 4; mi++)
#pragma unroll
        for (int ni = 0; ni < 4; ni++)
#pragma unroll
            for (int j = 0; j < 4; j++)
                xy[(size_t)(orow + mi * 16 + j) * NPROWS + ocol + ni * 16] = acc[mi][ni][j];
}

// ---------------- MFMA SYRK: G = Z Z^T from staged hi/lo (wave per 32x32 matrix) ----
__global__ __launch_bounds__(256) void syrk_mfma_kernel(const bf16x8* __restrict__ Ah,
                                                        const bf16x8* __restrict__ Al,
                                                        const bf16x8* __restrict__ Bh,
                                                        const bf16x8* __restrict__ Bl,
                                                        float* __restrict__ gxx,
                                                        float* __restrict__ gyy) {
    int ww = blockIdx.x * 4 + (threadIdx.x >> 6);
    int lane = threadIdx.x & 63;
    const bf16x8* hi;
    const bf16x8* lo;
    int nrows, row0;
    float* outp;
    if (ww < NQ) {
        hi = Ah; lo = Al; nrows = NQROWS; row0 = ww * 32;
        outp = gxx + (size_t)ww * (T * T);
    } else {
        hi = Bh; lo = Bl; nrows = NPROWS; row0 = (ww - NQ) * 32;
        outp = gyy + (size_t)(ww - NQ) * (T * T);
    }
    int r = lane & 15, g = lane >> 4;
    f32x4 acc[2][2];
    f32x4 zero = {0.f, 0.f, 0.f, 0.f};
    acc[0][0] = zero; acc[0][1] = zero; acc[1][0] = zero; acc[1][1] = zero;
    for (int t = 0; t < C / 32; t++) {
        size_t base = (size_t)(t * 4 + g) * nrows + row0 + r;
        bf16x8 h0 = hi[base], h1 = hi[base + 16];
        bf16x8 l0 = lo[base], l1 = lo[base + 16];
        acc[0][0] = __builtin_amdgcn_mfma_f32_16x16x32_bf16(h0, h0, acc[0][0], 0, 0, 0);
        acc[0][0] = __builtin_amdgcn_mfma_f32_16x16x32_bf16(h0, l0, acc[0][0], 0, 0, 0);
        acc[0][0] = __builtin_amdgcn_mfma_f32_16x16x32_bf16(l0, h0, acc[0][0], 0, 0, 0);
        acc[0][1] = __builtin_amdgcn_mfma_f32_16x16x32_bf16(h0, h1, acc[0][1], 0, 0, 0);
        acc[0][1] = __builtin_amdgcn_mfma_f32_16x16x32_bf16(h0, l1, acc[0][1], 0, 0, 0);
        acc[0][1] = __builtin_amdgcn_mfma_f32_16x16x32_bf16(l0, h1, acc[0][1], 0, 0, 0);
        acc[1][0] = __builtin_amdgcn_mfma_f32_16x16x32_bf16(h1, h0, acc[1][0], 0, 0, 0);
        acc[1][0] = __builtin_amdgcn_mfma_f32_16x16x32_bf16(h1, l0, acc[1][0], 0, 0, 0);
        acc[1][0] = __builtin_amdgcn_mfma_f32_16x16x32_bf16(l1, h0, acc[1][0], 0, 0, 0);
        acc[1][1] = __builtin_amdgcn_mfma_f32_16x16x32_bf16(h1, h1, acc[1][1], 0, 0, 0);
        acc[1][1] = __builtin_amdgcn_mfma_f32_16x16x32_bf16(h1, l1, acc[1][1], 0, 0, 0);
        acc[1][1] = __builtin_amdgcn_mfma_f32_16x16x32_bf16(l1, h1, acc[1][1], 0, 0, 0);
    }
#pragma unroll
    for (int mi = 0; mi < 2; mi++)
#pragma unroll
        for (int ni = 0; ni < 2; ni++)
#pragma unroll
            for (int j = 0; j < 4; j++)
                outp[(mi * 16 + g * 4 + j) * T + ni * 16 + r] = acc[mi][ni][j];
}

// ---------------- merged soft-DTW DP: one thread per 32x32 cost matrix ----------------
__global__ void softdtw_all_kernel(const float* __restrict__ xy, const float* __restrict__ gxx,
                                   const float* __restrict__ gyy, const float* __restrict__ x2,
                                   const float* __restrict__ y2, float* __restrict__ dxy,
                                   float* __restrict__ dxx, float* __restrict__ dyy) {
    int mm = blockIdx.x * 64 + threadIdx.x;
    if (mm >= NMM) return;
    const float* rterm;
    const float* cterm;
    const float* cptr;
    int cstride;
    float* outp;
    if (mm < NQ * NCLASS) {
        int q = mm / NCLASS, m = mm % NCLASS;
        rterm = x2 + q * T;
        cterm = y2 + m * T;
        cptr = xy + (size_t)(q * T) * NPROWS + m * T;
        cstride = NPROWS;
        outp = dxy + mm;
    } else if (mm < NQ * NCLASS + NQ) {
        int i = mm - NQ * NCLASS;
        rterm = x2 + i * T;
        cterm = rterm;
        cptr = gxx + (size_t)i * (T * T);
        cstride = T;
        outp = dxx + i;
    } else {
        int i = mm - NQ * NCLASS - NQ;
        rterm = y2 + i * T;
        cterm = rterm;
        cptr = gyy + (size_t)i * (T * T);
        cstride = T;
        outp = dyy + i;
    }
    float cj[T];
#pragma unroll
    for (int j = 0; j < T; j++) cj[j] = cterm[j];
    float Rp[T + 1];
    Rp[0] = 0.f;
#pragma unroll
    for (int j = 1; j <= T; j++) Rp[j] = BIG;
    for (int i = 0; i < T; i++) {
        float diag = Rp[0];
        Rp[0] = BIG;
        float left = BIG;
        float ai = rterm[i];
        const float4* crow4 = (const float4*)(cptr + (size_t)i * cstride);
        float cr[T];
#pragma unroll
        for (int jj = 0; jj < 8; jj++) {
            float4 v = crow4[jj];
            cr[jj * 4 + 0] = v.x; cr[jj * 4 + 1] = v.y;
            cr[jj * 4 + 2] = v.z; cr[jj * 4 + 3] = v.w;
        }
#pragma unroll
        for (int j = 0; j < T; j++) {
            float up = Rp[j + 1];
            float d = ai + cj[j] - 2.0f * cr[j];
            float mn = fminf(diag, fminf(up, left));
            float ssum = __expf((mn - diag) * INVG) + __expf((mn - up) * INVG) +
                         __expf((mn - left) * INVG);
            float rr = d + mn - GAMMA * __logf(ssum);
            diag = up;
            Rp[j + 1] = rr;
            left = rr;
        }
    }
    *outp = Rp[T];
}

// ---------------- finalize: dist, log-softmax, loss, acc ----------------
__global__ __launch_bounds__(512) void finalize_kernel(const float* __restrict__ dxy,
                                                       const float* __restrict__ dxx,
                                                       const float* __restrict__ dyy,
                                                       float* __restrict__ out) {
    __shared__ float sl[512];
    __shared__ float sa[512];
    int q = threadIdx.x;
    float bl = 0.f, fl = 0.f;
    if (q < NQ) {
        float dxxq = dxx[q];
        int cq = q / NQPC;
        float dd[NCLASS];
#pragma unroll
        for (int m = 0; m < NCLASS; m++)
            dd[m] = dxy[q * NCLASS + m] - 0.5f * (dxxq + dyy[m]);
        float best = dd[0];
        int bi = 0;
#pragma unroll
        for (int m = 1; m < NCLASS; m++) {
            if (dd[m] < best) { best = dd[m]; bi = m; }
        }
        float s = 0.f;
        float dcq = dd[0];
#pragma unroll
        for (int m = 0; m < NCLASS; m++) {
            s += __expf(best - dd[m]);
            if (m == cq) dcq = dd[m];
        }
        float lse = __logf(s) - best;
        bl = dcq + lse;
        out[2 + q] = bl;
        fl = (bi == cq) ? 1.f : 0.f;
    }
    sl[threadIdx.x] = bl;
    sa[threadIdx.x] = fl;
    __syncthreads();
    for (int off = 256; off; off >>= 1) {
        if (threadIdx.x < off) {
            sl[threadIdx.x] += sl[threadIdx.x + off];
            sa[threadIdx.x] += sa[threadIdx.x + off];
        }
        __syncthreads();
    }
    if (threadIdx.x == 0) {
        out[0] = sl[0] / (float)NQ;
        out[1] = sa[0] / (float)NQ;
    }
}

extern "C" void kernel_launch(void* const* d_in, const int* in_sizes, int n_in,
                              void* d_out, int out_size, void* d_ws, size_t ws_size,
                              hipStream_t stream) {
    const float* inp = (const float*)d_in[0];
    const int* target = (const int*)d_in[1];
    float* out = (float*)d_out;
    char* ws = (char*)d_ws;

    size_t off = 0;
    auto carve = [&](size_t bytes) {
        void* p = ws + off;
        off = (off + bytes + 255) & ~(size_t)255;
        return p;
    };
    int* order = (int*)carve(NTOT * sizeof(int));
    int* qsrc = (int*)carve(NQ * sizeof(int));
    float* x2 = (float*)carve((size_t)NQROWS * sizeof(float));
    float* y2 = (float*)carve((size_t)NPROWS * sizeof(float));
    float* xy = (float*)carve((size_t)NQROWS * NPROWS * sizeof(float));  // 41 MB
    float* gxx = (float*)carve((size_t)NQ * T * T * sizeof(float));
    float* gyy = (float*)carve((size_t)NCLASS * T * T * sizeof(float));
    float* dxy = (float*)carve((size_t)NQ * NCLASS * sizeof(float));
    float* dxx = (float*)carve((size_t)NQ * sizeof(float));
    float* dyy = (float*)carve((size_t)NCLASS * sizeof(float));
    bf16x8* Ah = (bf16x8*)carve((size_t)(C / 8) * NQROWS * 16);  // 65.5 MB
    bf16x8* Al = (bf16x8*)carve((size_t)(C / 8) * NQROWS * 16);
    bf16x8* Bh = (bf16x8*)carve((size_t)(C / 8) * NPROWS * 16);  // 2.6 MB
    bf16x8* Bl = (bf16x8*)carve((size_t)(C / 8) * NPROWS * 16);

    sort_kernel<<<1, 640, 0, stream>>>(target, order, qsrc);
    stage_b_kernel<<<NPROWS / 16, 256, 0, stream>>>(inp, order, Bh, Bl, y2);
    stage_a_kernel<<<NQROWS / 16, 256, 0, stream>>>(inp, qsrc, Ah, Al, x2);
    gemm_mfma_kernel<<<625, 256, 0, stream>>>(Ah, Al, Bh, Bl, xy);
    syrk_mfma_kernel<<<(NQ + NCLASS) / 4, 256, 0, stream>>>(Ah, Al, Bh, Bl, gxx, gyy);
    softdtw_all_kernel<<<(NMM + 63) / 64, 64, 0, stream>>>(xy, gxx, gyy, x2, y2, dxy, dxx, dyy);
    finalize_kernel<<<1, 512, 0, stream>>>(dxy, dxx, dyy, out);
}